// Round 3
// baseline (2723.290 us; speedup 1.0000x reference)
//
#include <hip/hip_runtime.h>
#include <hip/hip_bf16.h>
#include <cstdint>
#include <cstddef>

typedef unsigned short u16;
typedef u16 u16x4 __attribute__((ext_vector_type(4)));
typedef u16 u16x8 __attribute__((ext_vector_type(8)));
typedef __bf16 bf16x8 __attribute__((ext_vector_type(8)));
typedef float f32x4 __attribute__((ext_vector_type(4)));

__device__ __forceinline__ float bf2f(u16 v) {
    union { unsigned u; float f; } x; x.u = ((unsigned)v) << 16; return x.f;
}
__device__ __forceinline__ u16 f2bf(float f) {
    union { float f; unsigned u; } x; x.f = f;
    unsigned u = x.u;
    u += 0x7fffu + ((u >> 16) & 1u);   // round-to-nearest-even
    return (u16)(u >> 16);
}

// ---------------------------------------------------------------------------
// bitmap of unmasked positions: bm[b*S + p] = 1 iff p in unmasked_indices[b]
// ---------------------------------------------------------------------------
__global__ void build_bitmap(const int* __restrict__ unm, unsigned char* __restrict__ bm) {
    int tid = threadIdx.x;
    for (int i = tid; i < 4 * 2048; i += 256) bm[i] = 0;
    __syncthreads();
    for (int i = tid; i < 4 * 1024; i += 256) {
        int b = i >> 10;
        bm[b * 2048 + unm[i]] = 1;
    }
}

// tok2slot[b*S + s] = token index t if (b,s) is masked, else -1
__global__ void build_tokmap(const int* __restrict__ mi, int* __restrict__ tok2slot) {
    int tid = threadIdx.x;
    for (int i = tid; i < 8192; i += 256) tok2slot[i] = -1;
    __syncthreads();
    for (int i = tid; i < 4096; i += 256) {
        int b = i >> 10;
        tok2slot[b * 2048 + mi[i]] = i;
    }
}

// ---------------------------------------------------------------------------
// transpose f32 -> bf16: out[c][r] = bf16(in[r][c]); grid (C/64, R/64)
// ---------------------------------------------------------------------------
__global__ __launch_bounds__(256)
void transpose_g(const float* __restrict__ in, u16* __restrict__ out, int ldi, int ldo) {
    __shared__ u16 s[64][72];
    int tx = threadIdx.x & 15, ty = threadIdx.x >> 4;
    int c0 = blockIdx.x * 64, r0 = blockIdx.y * 64;
#pragma unroll
    for (int i = 0; i < 4; i++) {
        int row = ty + i * 16;
        f32x4 v = *(const f32x4*)(in + (size_t)(r0 + row) * ldi + c0 + tx * 4);
        u16x4 h;
#pragma unroll
        for (int j = 0; j < 4; j++) h[j] = f2bf(v[j]);
        *(u16x4*)&s[row][tx * 4] = h;
    }
    __syncthreads();
#pragma unroll
    for (int i = 0; i < 4; i++) {
        int cc = ty + i * 16;
        u16x4 v;
#pragma unroll
        for (int j = 0; j < 4; j++) v[j] = s[tx * 4 + j][cc];
        *(u16x4*)(out + (size_t)(c0 + cc) * ldo + r0 + tx * 4) = v;
    }
}

// ---------------------------------------------------------------------------
// gather neighbors + routing softmax.  One block per token (B*M = 4096).
// f32 inputs; writes X (bf16): [t][0:4096]=h_avg, [t][4096:8192]=h_mask;
// gate[t][8] (f32), cnt[t].
// ---------------------------------------------------------------------------
__global__ __launch_bounds__(256)
void gather_route(const float* __restrict__ hL, const float* __restrict__ Wr,
                  const float* __restrict__ br, const int* __restrict__ mask_idx,
                  const int* __restrict__ rptr, const unsigned char* __restrict__ bm,
                  u16* __restrict__ X, float* __restrict__ gate, int* __restrict__ cnt) {
    const int S = 2048, D = 4096;
    int t = blockIdx.x;
    int b = t >> 10;
    int tid = threadIdx.x;
    int a = mask_idx[t];
    int r = rptr[0];

    float avg[16];
#pragma unroll
    for (int i = 0; i < 16; i++) avg[i] = 0.f;
    int c = 0;
    for (int j = 0; j < 2 * r; j++) {
        int off = (j < r) ? (j - r) : (j - r + 1);
        int pos = a + off;
        bool ok = (pos >= 0) && (pos < S) && (bm[b * S + pos] != 0);
        if (ok) {
            c++;
            const float* rw = hL + (size_t)(b * S + pos) * D + tid * 16;
#pragma unroll
            for (int q = 0; q < 4; q++) {
                f32x4 v = *(const f32x4*)(rw + q * 4);
#pragma unroll
                for (int jj = 0; jj < 4; jj++) avg[q * 4 + jj] += v[jj];
            }
        }
    }
    float inv = 1.0f / (float)(c > 0 ? c : 1);

    const float* rm = hL + (size_t)(b * S + a) * D + tid * 16;
    float part[8];
#pragma unroll
    for (int k = 0; k < 8; k++) part[k] = 0.f;
#pragma unroll
    for (int q = 0; q < 4; q++) {
        f32x4 hm = *(const f32x4*)(rm + q * 4);
        u16x4 xa, xm;
#pragma unroll
        for (int jj = 0; jj < 4; jj++) {
            int d = tid * 16 + q * 4 + jj;
            float hv = hm[jj];
            f32x4 w0 = *(const f32x4*)(Wr + (size_t)d * 8);
            f32x4 w1 = *(const f32x4*)(Wr + (size_t)d * 8 + 4);
#pragma unroll
            for (int k = 0; k < 4; k++) { part[k] += hv * w0[k]; part[k + 4] += hv * w1[k]; }
            xa[jj] = f2bf(avg[q * 4 + jj] * inv);
            xm[jj] = f2bf(hv);
        }
        *(u16x4*)(X + (size_t)t * 8192 + tid * 16 + q * 4) = xa;
        *(u16x4*)(X + (size_t)t * 8192 + 4096 + tid * 16 + q * 4) = xm;
    }

    __shared__ float red[256][8];
#pragma unroll
    for (int k = 0; k < 8; k++) red[tid][k] = part[k];
    __syncthreads();
    for (int s = 128; s > 0; s >>= 1) {
        if (tid < s) {
#pragma unroll
            for (int k = 0; k < 8; k++) red[tid][k] += red[tid + s][k];
        }
        __syncthreads();
    }
    if (tid == 0) {
        float lg[8], mx = -1e30f;
#pragma unroll
        for (int k = 0; k < 8; k++) { lg[k] = red[0][k] + br[k]; mx = fmaxf(mx, lg[k]); }
        float sm = 0.f;
#pragma unroll
        for (int k = 0; k < 8; k++) { lg[k] = expf(lg[k] - mx); sm += lg[k]; }
        float is = 1.0f / sm;
#pragma unroll
        for (int k = 0; k < 8; k++) gate[t * 8 + k] = lg[k] * is;
        cnt[t] = c;
    }
}

// ---------------------------------------------------------------------------
// GEMM: C[m][n] = sum_k A[m][k]*Bt[n][k].  128x128 tile, BK=64, 256 thr.
// bf16 operands; LDS stride 72 u16 with XOR swizzle.
// MODE 1: out(bf16) = gatep[row*8] * gelu(acc + bias[col])
// MODE 2: out(f32)  = acc
// ---------------------------------------------------------------------------
template <int MODE>
__global__ __launch_bounds__(256)
void gemm_bt(const u16* __restrict__ A, const u16* __restrict__ Bt,
             void* __restrict__ out, const float* __restrict__ bias,
             const float* __restrict__ gatep, int K, int lda, int ldb, int ldc) {
    __shared__ __align__(16) u16 sA[128 * 72];
    __shared__ __align__(16) u16 sB[128 * 72];
    const int tid = threadIdx.x;
    const int w = tid >> 6, lane = tid & 63;
    const int wm = w >> 1, wn = w & 1;
    const int m0 = blockIdx.y * 128, n0 = blockIdx.x * 128;

    f32x4 acc[4][4];
#pragma unroll
    for (int i = 0; i < 4; i++)
#pragma unroll
        for (int j = 0; j < 4; j++) acc[i][j] = (f32x4){0.f, 0.f, 0.f, 0.f};

    const int sr = tid >> 3;   // 0..31 staging row base
    const int sc = tid & 7;    // 16B chunk within 64-k row

    for (int k0 = 0; k0 < K; k0 += 64) {
#pragma unroll
        for (int i = 0; i < 4; i++) {
            int r = sr + i * 32;
            u16x8 va = *(const u16x8*)(A + (size_t)(m0 + r) * lda + k0 + sc * 8);
            u16x8 vb = *(const u16x8*)(Bt + (size_t)(n0 + r) * ldb + k0 + sc * 8);
            int col = (sc ^ (r & 7)) * 8;
            *(u16x8*)(sA + r * 72 + col) = va;
            *(u16x8*)(sB + r * 72 + col) = vb;
        }
        __syncthreads();
#pragma unroll
        for (int ks = 0; ks < 2; ks++) {
            bf16x8 af[4], bf[4];
            int c8 = ks * 4 + (lane >> 4);
#pragma unroll
            for (int mi = 0; mi < 4; mi++) {
                int ra = wm * 64 + mi * 16 + (lane & 15);
                af[mi] = *(const bf16x8*)(sA + ra * 72 + ((c8 ^ (ra & 7)) * 8));
            }
#pragma unroll
            for (int ni = 0; ni < 4; ni++) {
                int rb = wn * 64 + ni * 16 + (lane & 15);
                bf[ni] = *(const bf16x8*)(sB + rb * 72 + ((c8 ^ (rb & 7)) * 8));
            }
#pragma unroll
            for (int mi = 0; mi < 4; mi++)
#pragma unroll
                for (int ni = 0; ni < 4; ni++)
                    acc[mi][ni] = __builtin_amdgcn_mfma_f32_16x16x32_bf16(
                        af[mi], bf[ni], acc[mi][ni], 0, 0, 0);
        }
        __syncthreads();
    }

    const int colb = n0 + wn * 64 + (lane & 15);
    const int rowb = m0 + wm * 64 + ((lane >> 4) << 2);
    if (MODE == 1) {
        u16* O = (u16*)out;
#pragma unroll
        for (int ni = 0; ni < 4; ni++) {
            int col = colb + ni * 16;
            float bv = bias[col];
#pragma unroll
            for (int mi = 0; mi < 4; mi++) {
#pragma unroll
                for (int rr = 0; rr < 4; rr++) {
                    int row = rowb + mi * 16 + rr;
                    float x = acc[mi][ni][rr] + bv;
                    float gel = 0.5f * x * (1.0f + erff(x * 0.70710678118654752f));
                    O[(size_t)row * ldc + col] = f2bf(gel * gatep[row * 8]);
                }
            }
        }
    } else {
        float* O = (float*)out;
#pragma unroll
        for (int ni = 0; ni < 4; ni++) {
            int col = colb + ni * 16;
#pragma unroll
            for (int mi = 0; mi < 4; mi++) {
#pragma unroll
                for (int rr = 0; rr < 4; rr++) {
                    int row = rowb + mi * 16 + rr;
                    O[(size_t)row * ldc + col] = acc[mi][ni][rr];
                }
            }
        }
    }
}

// ---------------------------------------------------------------------------
// LayerNorm (+ gate-weighted b2 bias) -> LNout (bf16 [4096][4096]).
// cnt==0 rows become zeros (matching reference's delta_h = 0).
// ---------------------------------------------------------------------------
__global__ __launch_bounds__(256)
void ln_kernel(const float* __restrict__ EO, const float* __restrict__ gate,
               const float* __restrict__ b2, const int* __restrict__ cnt,
               u16* __restrict__ LNout) {
    const int D = 4096;
    int t = blockIdx.x, tid = threadIdx.x;
    u16* orow = LNout + (size_t)t * D;
    if (cnt[t] == 0) {
        u16x4 z = (u16x4){0, 0, 0, 0};
#pragma unroll
        for (int i = 0; i < 4; i++) *(u16x4*)(orow + i * 1024 + tid * 4) = z;
        return;
    }
    float g[8];
#pragma unroll
    for (int k = 0; k < 8; k++) g[k] = gate[t * 8 + k];

    float vals[16];
    float sum = 0.f, sq = 0.f;
#pragma unroll
    for (int i = 0; i < 4; i++) {
        int d = i * 1024 + tid * 4;
        f32x4 v = *(const f32x4*)(EO + (size_t)t * D + d);
#pragma unroll
        for (int k = 0; k < 8; k++) {
            f32x4 bb = *(const f32x4*)(b2 + (size_t)k * D + d);
            float gk = g[k];
#pragma unroll
            for (int j = 0; j < 4; j++) v[j] += gk * bb[j];
        }
#pragma unroll
        for (int j = 0; j < 4; j++) { vals[i * 4 + j] = v[j]; sum += v[j]; sq += v[j] * v[j]; }
    }
    __shared__ float rs[256], rq[256];
    rs[tid] = sum; rq[tid] = sq;
    __syncthreads();
    for (int s = 128; s > 0; s >>= 1) {
        if (tid < s) { rs[tid] += rs[tid + s]; rq[tid] += rq[tid + s]; }
        __syncthreads();
    }
    float mean = rs[0] * (1.0f / 4096.0f);
    float var = rq[0] * (1.0f / 4096.0f) - mean * mean;
    float rstd = rsqrtf(var + 1e-5f);
#pragma unroll
    for (int i = 0; i < 4; i++) {
        int d = i * 1024 + tid * 4;
        u16x4 o;
#pragma unroll
        for (int j = 0; j < 4; j++) o[j] = f2bf((vals[i * 4 + j] - mean) * rstd);
        *(u16x4*)(orow + d) = o;
    }
}

// ---------------------------------------------------------------------------
// Final fill: writes EVERY element of d_out (f32).  One block per (b,s).
// ---------------------------------------------------------------------------
__global__ __launch_bounds__(256)
void final_fill(const u16* __restrict__ LNout, const int* __restrict__ tok2slot,
                float* __restrict__ out) {
    int p = blockIdx.x, tid = threadIdx.x;
    int slot = tok2slot[p];
    float* orow = out + (size_t)p * 4096;
    if (slot < 0) {
        f32x4 z = (f32x4){0.f, 0.f, 0.f, 0.f};
#pragma unroll
        for (int i = 0; i < 4; i++) *(f32x4*)(orow + i * 1024 + tid * 4) = z;
        return;
    }
    const u16* lrow = LNout + (size_t)slot * 4096;
#pragma unroll
    for (int i = 0; i < 4; i++) {
        u16x4 v = *(const u16x4*)(lrow + i * 1024 + tid * 4);
        f32x4 o;
#pragma unroll
        for (int j = 0; j < 4; j++) o[j] = bf2f(v[j]);
        *(f32x4*)(orow + i * 1024 + tid * 4) = o;
    }
}

// ---------------------------------------------------------------------------
// Memory plan:
//   d_ws (peak exactly 128 MiB):
//     [0,   64Mi)  X (bf16 [4096][8192])  -> reused as EO (f32 [4096][4096])
//     [64Mi,128Mi) HG (bf16 [4096][8192]) -> after GEMM2 reused as:
//                    LNout (bf16 [4096][4096], 32 MiB) + tok2slot (i32[8192])
//   d_out used as scratch until final_fill (f32 [4][2048][4096] = 128 MiB):
//     [64Mi,80Mi)  WT (bf16 [1024][8192]) transpose staging
//     [80Mi, ...)  gate (f32 [4096][8]), cnt (i32[4096]), bm (u8[8192])
//   final_fill writes every d_out element, reading only ws-resident data.
// ---------------------------------------------------------------------------
extern "C" void kernel_launch(void* const* d_in, const int* in_sizes, int n_in,
                              void* d_out, int out_size, void* d_ws, size_t ws_size,
                              hipStream_t stream) {
    const float* hL = (const float*)d_in[0];
    const float* Wr = (const float*)d_in[1];
    const float* br = (const float*)d_in[2];
    const float* W1 = (const float*)d_in[3];
    const float* b1 = (const float*)d_in[4];
    const float* W2 = (const float*)d_in[5];
    const float* b2 = (const float*)d_in[6];
    const int* mi = (const int*)d_in[7];
    const int* ui = (const int*)d_in[8];
    const int* rr = (const int*)d_in[9];

    char* ws = (char*)d_ws;
    u16* X = (u16*)ws;
    float* EO = (float*)ws;
    u16* HG = (u16*)(ws + 67108864);
    u16* LNout = HG;
    int* tok2slot = (int*)(ws + 67108864 + 33554432);

    char* ob = (char*)d_out;
    u16* WT = (u16*)(ob + 67108864);
    float* gate = (float*)(ob + 83886080);
    int* cnt = (int*)(ob + 83886080 + 131072);
    unsigned char* bm = (unsigned char*)(ob + 83886080 + 131072 + 16384);

    build_bitmap<<<dim3(1), dim3(256), 0, stream>>>(ui, bm);
    gather_route<<<dim3(4096), dim3(256), 0, stream>>>(hL, Wr, br, mi, rr, bm, X, gate, cnt);

    // GEMM1 per expert: HG[:, e*1024:(e+1)*1024] = gate[:,e]*gelu(X @ W1[e] + b1[e])
    for (int e = 0; e < 8; e++) {
        transpose_g<<<dim3(16, 128), dim3(256), 0, stream>>>(
            W1 + (size_t)e * 8192 * 1024, WT, 1024, 8192);
        gemm_bt<1><<<dim3(8, 32), dim3(256), 0, stream>>>(
            X, WT, (void*)(HG + e * 1024), b1 + e * 1024, gate + e,
            8192, 8192, 8192, 8192);
    }
    // GEMM2 per 1024-col chunk: EO[:, c*1024:(c+1)*1024] = HG @ W2flat[:, chunk]
    for (int c = 0; c < 4; c++) {
        transpose_g<<<dim3(16, 128), dim3(256), 0, stream>>>(
            W2 + c * 1024, WT, 4096, 8192);
        gemm_bt<2><<<dim3(8, 32), dim3(256), 0, stream>>>(
            HG, WT, (void*)(EO + c * 1024), (const float*)nullptr, (const float*)nullptr,
            8192, 8192, 8192, 4096);
    }
    build_tokmap<<<dim3(1), dim3(256), 0, stream>>>(mi, tok2slot);
    ln_kernel<<<dim3(4096), dim3(256), 0, stream>>>(EO, gate, b2, cnt, LNout);
    final_fill<<<dim3(8192), dim3(256), 0, stream>>>(LNout, tok2slot, (float*)d_out);
}